// Round 12
// baseline (212.517 us; speedup 1.0000x reference)
//
#include <hip/hip_runtime.h>
#include <math.h>

// CIN (xDeepFM) — split-bf16 16x16x32 MFMA, REGISTER-DIRECT A-fragments.
// y[b,o,d] = bias[o] + sum_f x[b,f,d] * ( sum_h W[o,f*H+h] * h_in[b,h,d] )
//   W*h ~= Whi*hhi + Whi*hlo + Wlo*hhi   (split bf16, lo*lo dropped)
// No global_load_lds in the hot loop: wave w's A-fragment for chunk c is ONE
// coalesced 1KB load from the fragment-linear W image (L2-resident), straight
// to VGPRs, ping-pong slots, prefetch distance 2 bodies. No asm waitcnts —
// the compiler inserts exact vmcnt waits for plain loads. LDS holds only the
// 8KB x-tile (one prologue gll + the only barrier).
// B=512, F=32, D=64, O=128; H0=32 (h=x), H1=H2=128; NPASS=H/32, NIT=NPASS*32.

typedef __attribute__((ext_vector_type(8))) short bf16x8;
typedef __attribute__((ext_vector_type(4))) float f32x4;
typedef __attribute__((ext_vector_type(4))) unsigned short u16x4;

#define HT_LO 4194304   // shorts: 512*64*128 (offset of lo plane)

__device__ __forceinline__ unsigned short f2bf(float f) {
  unsigned int u = __float_as_uint(f);
  u = (u + 0x7fffu + ((u >> 16) & 1u)) >> 16;   // RNE
  return (unsigned short)u;
}
__device__ __forceinline__ float bf2f(unsigned short h) {
  return __uint_as_float((unsigned int)h << 16);
}

__device__ __forceinline__ void gll16(const void* g, void* l) {
  __builtin_amdgcn_global_load_lds(
      (const __attribute__((address_space(1))) unsigned int*)g,
      (__attribute__((address_space(3))) unsigned int*)l, 16, 0, 0);
}

// ---- pre-pass: repack W (fp32, row-major 128xK) into split-bf16 image,
// chunk-sequential in iteration order: chunk c = pass*32 + f at 16B-unit c*1024.
// in-chunk (16B units): hi plane at [0,512) = mt*64+lane, lo plane at [512,1024).
// element: W[o = mt*16+(l&15)][kcol = f*H + pass*32 + (l>>4)*8 + j]
__global__ void repack_w_kernel(const float* __restrict__ W, unsigned short* __restrict__ dst,
                                int H, int nthreads)
{
  const int t = blockIdx.x * 256 + threadIdx.x;
  if (t >= nthreads) return;
  const int K = 32 * H;
  const int idx = t & 511;
  const int c   = t >> 9;
  const int pass = c >> 5, f = c & 31;
  const int mt = idx >> 6, l = idx & 63;
  const int o = mt * 16 + (l & 15);
  const int kcol = f * H + pass * 32 + ((l >> 4) & 3) * 8;
  const float* s = W + (size_t)o * K + kcol;
  u16x4 h0, h1, l0, l1;
#pragma unroll
  for (int j = 0; j < 4; ++j) {
    float v = s[j];
    unsigned short hb = f2bf(v);
    h0[j] = hb; l0[j] = f2bf(v - bf2f(hb));
    v = s[4 + j];
    hb = f2bf(v);
    h1[j] = hb; l1[j] = f2bf(v - bf2f(hb));
  }
  const size_t uhi = (size_t)c * 1024 + idx;         // 16B units
  const size_t ulo = (size_t)c * 1024 + 512 + idx;
  *(u16x4*)(dst + uhi * 8)     = h0;
  *(u16x4*)(dst + uhi * 8 + 4) = h1;
  *(u16x4*)(dst + ulo * 8)     = l0;
  *(u16x4*)(dst + ulo * 8 + 4) = l1;
}

// one body: scales first (hoistable LDS reads), 12 MFMA from slot regs,
// then prefetch chunk CNEXT into the consumed slot (distance 2), Y update.
#define BODY(FCUR, AHc, ALc, CNEXT, AHd, ALd)                                   \
  {                                                                             \
    const float sc0 = lx[(FCUR) * 64 +  0 + li];                                \
    const float sc1 = lx[(FCUR) * 64 + 16 + li];                                \
    const float sc2 = lx[(FCUR) * 64 + 32 + li];                                \
    const float sc3 = lx[(FCUR) * 64 + 48 + li];                                \
    f32x4 G[4];                                                                 \
    __builtin_amdgcn_s_setprio(1);                                              \
    _Pragma("unroll")                                                           \
    for (int nt = 0; nt < 4; ++nt) {                                            \
      G[nt] = __builtin_amdgcn_mfma_f32_16x16x32_bf16(AHc, Bh[nt], zero4, 0, 0, 0); \
      G[nt] = __builtin_amdgcn_mfma_f32_16x16x32_bf16(AHc, Bl[nt], G[nt], 0, 0, 0); \
      G[nt] = __builtin_amdgcn_mfma_f32_16x16x32_bf16(ALc, Bh[nt], G[nt], 0, 0, 0); \
    }                                                                           \
    __builtin_amdgcn_s_setprio(0);                                              \
    {                                                                           \
      size_t cn_ = (size_t)(CNEXT);                                             \
      if (cn_ > (size_t)(NIT - 1)) cn_ = (size_t)(NIT - 1);                     \
      AHd = Abase[cn_ * 1024];                                                  \
      ALd = Abase[cn_ * 1024 + 512];                                            \
    }                                                                           \
    Y[0] += G[0] * sc0;                                                         \
    Y[1] += G[1] * sc1;                                                         \
    Y[2] += G[2] * sc2;                                                         \
    Y[3] += G[3] * sc3;                                                         \
  }

// ---- main layer kernel ----
// grid 512 x 512 threads; block = batch b; wave w owns o in [16w, 16w+16).
// LDS: 8KB raw x[b] only.
template<int H, int NPASS, bool FIRST, bool STORE_H>
__global__ __launch_bounds__(512, 4) void cin_mfma_layer(
    const unsigned short* __restrict__ Wimg,
    const float* __restrict__ x,               // (B,32,64) fp32
    const unsigned short* __restrict__ hTin,   // hi plane; lo at +HT_LO  (null if FIRST)
    const float* __restrict__ bias,
    unsigned short* __restrict__ hTout,        // hi plane; lo at +HT_LO
    float* __restrict__ outs, int col_off)
{
  constexpr int NIT = NPASS * 32;
  __shared__ char lds[8192];
  const int tid = threadIdx.x;
  const int w = tid >> 6, l = tid & 63, g = l >> 4, li = l & 15;
  const int b = blockIdx.x;
  const float* lx = (const float*)lds;

  // prologue: stage x[b] (8KB, one gll round, lane-linear), publish via barrier
  gll16(x + (size_t)b * 2048 + tid * 4, lds + w * 1024);

  f32x4 Y[4];
#pragma unroll
  for (int nt = 0; nt < 4; ++nt) Y[nt] = (f32x4){0.f, 0.f, 0.f, 0.f};
  const f32x4 zero4 = (f32x4){0.f, 0.f, 0.f, 0.f};
  bf16x8 Bh[4], Bl[4];

  asm volatile("s_waitcnt vmcnt(0)" ::: "memory");
  __builtin_amdgcn_s_barrier();   // the ONLY barrier

  if constexpr (FIRST) {
    // build split B-fragments from raw x in LDS (h == x; NPASS==1)
#pragma unroll
    for (int nt = 0; nt < 4; ++nt) {
      union { bf16x8 v; unsigned short u[8]; } th, tl;
#pragma unroll
      for (int j = 0; j < 8; ++j) {
        const float xv = lx[(g * 8 + j) * 64 + nt * 16 + li];
        const unsigned short hb = f2bf(xv);
        th.u[j] = hb; tl.u[j] = f2bf(xv - bf2f(hb));
      }
      Bh[nt] = th.v; Bl[nt] = tl.v;
    }
  }

  // wave's A-fragment base: 16B unit (w*64 + l); hi at c*1024, lo at +512
  const bf16x8* Abase = (const bf16x8*)Wimg + (w * 64 + l);

  // preload A(0) -> slot a, A(1) -> slot b
  bf16x8 AHa = Abase[0],    ALa = Abase[512];
  bf16x8 AHb = Abase[1024], ALb = Abase[1536];

  for (int pass = 0; pass < NPASS; ++pass) {
    if constexpr (!FIRST) {
      // B-fragments for this pass (h rows [pass*32, pass*32+32), reused over f)
#pragma unroll
      for (int nt = 0; nt < 4; ++nt) {
        const size_t off = (size_t)b * 8192 + (size_t)(nt * 16 + li) * 128
                         + pass * 32 + g * 8;
        Bh[nt] = *(const bf16x8*)(hTin + off);
        Bl[nt] = *(const bf16x8*)(hTin + HT_LO + off);
      }
    }
    const int cb = pass * 32;
#pragma unroll 1
    for (int fo = 0; fo < 32; fo += 2) {
      BODY(fo,     AHa, ALa, cb + fo + 2, AHa, ALa)
      BODY(fo + 1, AHb, ALb, cb + fo + 3, AHb, ALb)
    }
  }

  // ---- epilogue: bias, split-hT store, outs row-sums ----
  const f32x4 bv = *(const f32x4*)(bias + w * 16 + g * 4);
#pragma unroll
  for (int nt = 0; nt < 4; ++nt) Y[nt] += bv;

  if constexpr (STORE_H) {
#pragma unroll
    for (int nt = 0; nt < 4; ++nt) {
      const int d = nt * 16 + li;
      u16x4 ph, pl;
#pragma unroll
      for (int j = 0; j < 4; ++j) {
        const unsigned short hb = f2bf(Y[nt][j]);
        ph[j] = hb; pl[j] = f2bf(Y[nt][j] - bf2f(hb));
      }
      const size_t off = (size_t)b * 8192 + (size_t)d * 128 + w * 16 + g * 4;
      *(u16x4*)(hTout + off)         = ph;
      *(u16x4*)(hTout + HT_LO + off) = pl;
    }
  }

  {
    f32x4 s = Y[0] + Y[1] + Y[2] + Y[3];
#pragma unroll
    for (int m = 1; m < 16; m <<= 1) {
      s.x += __shfl_xor(s.x, m, 16);
      s.y += __shfl_xor(s.y, m, 16);
      s.z += __shfl_xor(s.z, m, 16);
      s.w += __shfl_xor(s.w, m, 16);
    }
    if (li == 0)
      *(f32x4*)(outs + (size_t)b * 384 + col_off + w * 16 + g * 4) = s;
  }
}

// ---- final: out[b] = sigmoid( relu(outs[b,:]) . Wout + bout ) ----
__global__ __launch_bounds__(64) void cin_final_kernel(
    const float* __restrict__ outs, const float* __restrict__ Wout,
    const float* __restrict__ bout, float* __restrict__ out)
{
  const int b = blockIdx.x;
  const int lane = threadIdx.x;
  float p = 0.f;
  for (int j = lane; j < 384; j += 64) {
    float v = outs[(size_t)b * 384 + j];
    v = v > 0.f ? v : 0.f;
    p = fmaf(v, Wout[j], p);
  }
#pragma unroll
  for (int m = 32; m; m >>= 1) p += __shfl_xor(p, m, 64);
  if (lane == 0) {
    const float t = p + bout[0];
    out[b] = 1.f / (1.f + expf(-t));
  }
}

extern "C" void kernel_launch(void* const* d_in, const int* in_sizes, int n_in,
                              void* d_out, int out_size, void* d_ws, size_t ws_size,
                              hipStream_t stream)
{
  const float* x    = (const float*)d_in[0];
  const float* W0   = (const float*)d_in[1];
  const float* b0   = (const float*)d_in[2];
  const float* W1   = (const float*)d_in[3];
  const float* b1   = (const float*)d_in[4];
  const float* W2   = (const float*)d_in[5];
  const float* b2   = (const float*)d_in[6];
  const float* Wout = (const float*)d_in[7];
  const float* bout = (const float*)d_in[8];
  float* out = (float*)d_out;

  char* ws = (char*)d_ws;
  unsigned short* hT1  = (unsigned short*)ws;                    // 16 MB (hi+lo)
  unsigned short* hT2  = (unsigned short*)(ws + (16 << 20));     // 16 MB
  float*          outs = (float*)        (ws + (32 << 20));      // 768 KB
  unsigned short* Wi0  = (unsigned short*)(ws + (33 << 20));               // 512 KB
  unsigned short* Wi1  = (unsigned short*)(ws + (33 << 20) + (1 << 19));   // 2 MB
  unsigned short* Wi2  = (unsigned short*)(ws + (33 << 20) + (1 << 19) + (2 << 20)); // 2 MB

  // nthreads = (K/32 chunks) * 512
  repack_w_kernel<<<64,  256, 0, stream>>>(W0, Wi0, 32,  16384);
  repack_w_kernel<<<256, 256, 0, stream>>>(W1, Wi1, 128, 65536);
  repack_w_kernel<<<256, 256, 0, stream>>>(W2, Wi2, 128, 65536);

  cin_mfma_layer<32,  1, true,  true ><<<512, 512, 0, stream>>>(Wi0, x, nullptr, b0, hT1, outs, 0);
  cin_mfma_layer<128, 4, false, true ><<<512, 512, 0, stream>>>(Wi1, x, hT1,    b1, hT2, outs, 128);
  cin_mfma_layer<128, 4, false, false><<<512, 512, 0, stream>>>(Wi2, x, hT2,    b2, nullptr, outs, 256);

  cin_final_kernel<<<512, 64, 0, stream>>>(outs, Wout, bout, out);
}

// Round 13
// 210.450 us; speedup vs baseline: 1.0098x; 1.0098x over previous
//
#include <hip/hip_runtime.h>
#include <math.h>

// CIN (xDeepFM) — split-bf16 16x16x32 MFMA, register-direct A-fragments,
// INTERLEAVED MFMA issue order (term-outer, nt-inner): dependent ops on the
// same accumulator are 4 instructions apart -> dep-latency hidden at issue.
// y[b,o,d] = bias[o] + sum_f x[b,f,d] * ( sum_h W[o,f*H+h] * h_in[b,h,d] )
//   W*h ~= Whi*hhi + Whi*hlo + Wlo*hhi   (split bf16, lo*lo dropped)
// B=512, F=32, D=64, O=128; H0=32 (h=x), H1=H2=128; NPASS=H/32, NIT=NPASS*32.

typedef __attribute__((ext_vector_type(8))) short bf16x8;
typedef __attribute__((ext_vector_type(4))) float f32x4;
typedef __attribute__((ext_vector_type(4))) unsigned short u16x4;

#define HT_LO 4194304   // shorts: 512*64*128 (offset of lo plane)

__device__ __forceinline__ unsigned short f2bf(float f) {
  unsigned int u = __float_as_uint(f);
  u = (u + 0x7fffu + ((u >> 16) & 1u)) >> 16;   // RNE
  return (unsigned short)u;
}
__device__ __forceinline__ float bf2f(unsigned short h) {
  return __uint_as_float((unsigned int)h << 16);
}

__device__ __forceinline__ void gll16(const void* g, void* l) {
  __builtin_amdgcn_global_load_lds(
      (const __attribute__((address_space(1))) unsigned int*)g,
      (__attribute__((address_space(3))) unsigned int*)l, 16, 0, 0);
}

// ---- pre-pass: repack W (fp32, row-major 128xK) into split-bf16 image,
// chunk-sequential in iteration order: chunk c = pass*32 + f at 16B-unit c*1024.
// in-chunk (16B units): hi plane at [0,512) = mt*64+lane, lo plane at [512,1024).
// element: W[o = mt*16+(l&15)][kcol = f*H + pass*32 + (l>>4)*8 + j]
__global__ void repack_w_kernel(const float* __restrict__ W, unsigned short* __restrict__ dst,
                                int H, int nthreads)
{
  const int t = blockIdx.x * 256 + threadIdx.x;
  if (t >= nthreads) return;
  const int K = 32 * H;
  const int idx = t & 511;
  const int c   = t >> 9;
  const int pass = c >> 5, f = c & 31;
  const int mt = idx >> 6, l = idx & 63;
  const int o = mt * 16 + (l & 15);
  const int kcol = f * H + pass * 32 + ((l >> 4) & 3) * 8;
  const float* s = W + (size_t)o * K + kcol;
  u16x4 h0, h1, l0, l1;
#pragma unroll
  for (int j = 0; j < 4; ++j) {
    float v = s[j];
    unsigned short hb = f2bf(v);
    h0[j] = hb; l0[j] = f2bf(v - bf2f(hb));
    v = s[4 + j];
    hb = f2bf(v);
    h1[j] = hb; l1[j] = f2bf(v - bf2f(hb));
  }
  const size_t uhi = (size_t)c * 1024 + idx;         // 16B units
  const size_t ulo = (size_t)c * 1024 + 512 + idx;
  *(u16x4*)(dst + uhi * 8)     = h0;
  *(u16x4*)(dst + uhi * 8 + 4) = h1;
  *(u16x4*)(dst + ulo * 8)     = l0;
  *(u16x4*)(dst + ulo * 8 + 4) = l1;
}

// one body: scales first (hoistable LDS reads), 12 MFMA in INTERLEAVED order
// (4 independent accumulators between dependent pairs), prefetch chunk CNEXT
// into the consumed slot (distance 2), Y update.
#define BODY(FCUR, AHc, ALc, CNEXT, AHd, ALd)                                   \
  {                                                                             \
    const float sc0 = lx[(FCUR) * 64 +  0 + li];                                \
    const float sc1 = lx[(FCUR) * 64 + 16 + li];                                \
    const float sc2 = lx[(FCUR) * 64 + 32 + li];                                \
    const float sc3 = lx[(FCUR) * 64 + 48 + li];                                \
    f32x4 G0, G1, G2, G3;                                                       \
    __builtin_amdgcn_s_setprio(1);                                              \
    G0 = __builtin_amdgcn_mfma_f32_16x16x32_bf16(AHc, Bh[0], zero4, 0, 0, 0);   \
    G1 = __builtin_amdgcn_mfma_f32_16x16x32_bf16(AHc, Bh[1], zero4, 0, 0, 0);   \
    G2 = __builtin_amdgcn_mfma_f32_16x16x32_bf16(AHc, Bh[2], zero4, 0, 0, 0);   \
    G3 = __builtin_amdgcn_mfma_f32_16x16x32_bf16(AHc, Bh[3], zero4, 0, 0, 0);   \
    G0 = __builtin_amdgcn_mfma_f32_16x16x32_bf16(AHc, Bl[0], G0, 0, 0, 0);      \
    G1 = __builtin_amdgcn_mfma_f32_16x16x32_bf16(AHc, Bl[1], G1, 0, 0, 0);      \
    G2 = __builtin_amdgcn_mfma_f32_16x16x32_bf16(AHc, Bl[2], G2, 0, 0, 0);      \
    G3 = __builtin_amdgcn_mfma_f32_16x16x32_bf16(AHc, Bl[3], G3, 0, 0, 0);      \
    G0 = __builtin_amdgcn_mfma_f32_16x16x32_bf16(ALc, Bh[0], G0, 0, 0, 0);      \
    G1 = __builtin_amdgcn_mfma_f32_16x16x32_bf16(ALc, Bh[1], G1, 0, 0, 0);      \
    G2 = __builtin_amdgcn_mfma_f32_16x16x32_bf16(ALc, Bh[2], G2, 0, 0, 0);      \
    G3 = __builtin_amdgcn_mfma_f32_16x16x32_bf16(ALc, Bh[3], G3, 0, 0, 0);      \
    __builtin_amdgcn_s_setprio(0);                                              \
    {                                                                           \
      size_t cn_ = (size_t)(CNEXT);                                             \
      if (cn_ > (size_t)(NIT - 1)) cn_ = (size_t)(NIT - 1);                     \
      AHd = Abase[cn_ * 1024];                                                  \
      ALd = Abase[cn_ * 1024 + 512];                                            \
    }                                                                           \
    Y[0] += G0 * sc0;                                                           \
    Y[1] += G1 * sc1;                                                           \
    Y[2] += G2 * sc2;                                                           \
    Y[3] += G3 * sc3;                                                           \
  }

// ---- main layer kernel ----
// grid 512 x 512 threads; block = batch b; wave w owns o in [16w, 16w+16).
// LDS: 8KB raw x[b] only.
template<int H, int NPASS, bool FIRST, bool STORE_H>
__global__ __launch_bounds__(512, 4) void cin_mfma_layer(
    const unsigned short* __restrict__ Wimg,
    const float* __restrict__ x,               // (B,32,64) fp32
    const unsigned short* __restrict__ hTin,   // hi plane; lo at +HT_LO  (null if FIRST)
    const float* __restrict__ bias,
    unsigned short* __restrict__ hTout,        // hi plane; lo at +HT_LO
    float* __restrict__ outs, int col_off)
{
  constexpr int NIT = NPASS * 32;
  __shared__ char lds[8192];
  const int tid = threadIdx.x;
  const int w = tid >> 6, l = tid & 63, g = l >> 4, li = l & 15;
  const int b = blockIdx.x;
  const float* lx = (const float*)lds;

  // prologue: stage x[b] (8KB, one gll round, lane-linear), publish via barrier
  gll16(x + (size_t)b * 2048 + tid * 4, lds + w * 1024);

  f32x4 Y[4];
#pragma unroll
  for (int nt = 0; nt < 4; ++nt) Y[nt] = (f32x4){0.f, 0.f, 0.f, 0.f};
  const f32x4 zero4 = (f32x4){0.f, 0.f, 0.f, 0.f};
  bf16x8 Bh[4], Bl[4];

  asm volatile("s_waitcnt vmcnt(0)" ::: "memory");
  __builtin_amdgcn_s_barrier();   // the ONLY barrier

  if constexpr (FIRST) {
    // build split B-fragments from raw x in LDS (h == x; NPASS==1)
#pragma unroll
    for (int nt = 0; nt < 4; ++nt) {
      union { bf16x8 v; unsigned short u[8]; } th, tl;
#pragma unroll
      for (int j = 0; j < 8; ++j) {
        const float xv = lx[(g * 8 + j) * 64 + nt * 16 + li];
        const unsigned short hb = f2bf(xv);
        th.u[j] = hb; tl.u[j] = f2bf(xv - bf2f(hb));
      }
      Bh[nt] = th.v; Bl[nt] = tl.v;
    }
  }

  // wave's A-fragment base: 16B unit (w*64 + l); hi at c*1024, lo at +512
  const bf16x8* Abase = (const bf16x8*)Wimg + (w * 64 + l);

  // preload A(0) -> slot a, A(1) -> slot b
  bf16x8 AHa = Abase[0],    ALa = Abase[512];
  bf16x8 AHb = Abase[1024], ALb = Abase[1536];

  for (int pass = 0; pass < NPASS; ++pass) {
    if constexpr (!FIRST) {
      // B-fragments for this pass (h rows [pass*32, pass*32+32), reused over f)
#pragma unroll
      for (int nt = 0; nt < 4; ++nt) {
        const size_t off = (size_t)b * 8192 + (size_t)(nt * 16 + li) * 128
                         + pass * 32 + g * 8;
        Bh[nt] = *(const bf16x8*)(hTin + off);
        Bl[nt] = *(const bf16x8*)(hTin + HT_LO + off);
      }
    }
    const int cb = pass * 32;
#pragma unroll 1
    for (int fo = 0; fo < 32; fo += 2) {
      BODY(fo,     AHa, ALa, cb + fo + 2, AHa, ALa)
      BODY(fo + 1, AHb, ALb, cb + fo + 3, AHb, ALb)
    }
  }

  // ---- epilogue: bias, split-hT store, outs row-sums ----
  const f32x4 bv = *(const f32x4*)(bias + w * 16 + g * 4);
#pragma unroll
  for (int nt = 0; nt < 4; ++nt) Y[nt] += bv;

  if constexpr (STORE_H) {
#pragma unroll
    for (int nt = 0; nt < 4; ++nt) {
      const int d = nt * 16 + li;
      u16x4 ph, pl;
#pragma unroll
      for (int j = 0; j < 4; ++j) {
        const unsigned short hb = f2bf(Y[nt][j]);
        ph[j] = hb; pl[j] = f2bf(Y[nt][j] - bf2f(hb));
      }
      const size_t off = (size_t)b * 8192 + (size_t)d * 128 + w * 16 + g * 4;
      *(u16x4*)(hTout + off)         = ph;
      *(u16x4*)(hTout + HT_LO + off) = pl;
    }
  }

  {
    f32x4 s = Y[0] + Y[1] + Y[2] + Y[3];
#pragma unroll
    for (int m = 1; m < 16; m <<= 1) {
      s.x += __shfl_xor(s.x, m, 16);
      s.y += __shfl_xor(s.y, m, 16);
      s.z += __shfl_xor(s.z, m, 16);
      s.w += __shfl_xor(s.w, m, 16);
    }
    if (li == 0)
      *(f32x4*)(outs + (size_t)b * 384 + col_off + w * 16 + g * 4) = s;
  }
}

// ---- final: out[b] = sigmoid( relu(outs[b,:]) . Wout + bout ) ----
__global__ __launch_bounds__(64) void cin_final_kernel(
    const float* __restrict__ outs, const float* __restrict__ Wout,
    const float* __restrict__ bout, float* __restrict__ out)
{
  const int b = blockIdx.x;
  const int lane = threadIdx.x;
  float p = 0.f;
  for (int j = lane; j < 384; j += 64) {
    float v = outs[(size_t)b * 384 + j];
    v = v > 0.f ? v : 0.f;
    p = fmaf(v, Wout[j], p);
  }
#pragma unroll
  for (int m = 32; m; m >>= 1) p += __shfl_xor(p, m, 64);
  if (lane == 0) {
    const float t = p + bout[0];
    out[b] = 1.f / (1.f + expf(-t));
  }
}

extern "C" void kernel_launch(void* const* d_in, const int* in_sizes, int n_in,
                              void* d_out, int out_size, void* d_ws, size_t ws_size,
                              hipStream_t stream)
{
  const float* x    = (const float*)d_in[0];
  const float* W0   = (const float*)d_in[1];
  const float* b0   = (const float*)d_in[2];
  const float* W1   = (const float*)d_in[3];
  const float* b1   = (const float*)d_in[4];
  const float* W2   = (const float*)d_in[5];
  const float* b2   = (const float*)d_in[6];
  const float* Wout = (const float*)d_in[7];
  const float* bout = (const float*)d_in[8];
  float* out = (float*)d_out;

  char* ws = (char*)d_ws;
  unsigned short* hT1  = (unsigned short*)ws;                    // 16 MB (hi+lo)
  unsigned short* hT2  = (unsigned short*)(ws + (16 << 20));     // 16 MB
  float*          outs = (float*)        (ws + (32 << 20));      // 768 KB
  unsigned short* Wi0  = (unsigned short*)(ws + (33 << 20));               // 512 KB
  unsigned short* Wi1  = (unsigned short*)(ws + (33 << 20) + (1 << 19));   // 2 MB
  unsigned short* Wi2  = (unsigned short*)(ws + (33 << 20) + (1 << 19) + (2 << 20)); // 2 MB

  // nthreads = (K/32 chunks) * 512
  repack_w_kernel<<<64,  256, 0, stream>>>(W0, Wi0, 32,  16384);
  repack_w_kernel<<<256, 256, 0, stream>>>(W1, Wi1, 128, 65536);
  repack_w_kernel<<<256, 256, 0, stream>>>(W2, Wi2, 128, 65536);

  cin_mfma_layer<32,  1, true,  true ><<<512, 512, 0, stream>>>(Wi0, x, nullptr, b0, hT1, outs, 0);
  cin_mfma_layer<128, 4, false, true ><<<512, 512, 0, stream>>>(Wi1, x, hT1,    b1, hT2, outs, 128);
  cin_mfma_layer<128, 4, false, false><<<512, 512, 0, stream>>>(Wi2, x, hT2,    b2, nullptr, outs, 256);

  cin_final_kernel<<<512, 64, 0, stream>>>(outs, Wout, bout, out);
}